// Round 1
// baseline (837.711 us; speedup 1.0000x reference)
//
#include <hip/hip_runtime.h>
#include <hip/hip_bf16.h>

#define TOKENS 16384
#define MDIM   1024
#define HDIM   4096
#define NEXP   8
#define EGRP   4          // experts per GEMM group (2 groups)
#define CAP    2048
#define NKT1   (MDIM / 64)   // 16 K-tiles for GEMM1
#define NKT2   (HDIM / 64)   // 64 K-tiles for GEMM2

typedef __attribute__((ext_vector_type(8))) short bf16x8;  // 8 bf16 = 4 VGPR
typedef __attribute__((ext_vector_type(4))) float f32x4;

__device__ __forceinline__ short f2bf(float x) {
  unsigned u = __float_as_uint(x);
  unsigned r = (u + 0x7fffu + ((u >> 16) & 1u)) >> 16;
  return (short)r;
}

// round bits to bf16 boundary (RNE), result in high 16 bits
__device__ __forceinline__ unsigned bfbits(float x) {
  unsigned u = __float_as_uint(x);
  return u + 0x7fffu + ((u >> 16) & 1u);
}

__device__ __forceinline__ float gelu_f(float x) {
  // jax.nn.gelu approximate=True
  float u = 1.5957691216057308f * (x + 0.044715f * x * x * x);
  float e = __expf(u);
  return x * (1.f - 1.f / (e + 1.f));
}

// ---------------- gating: logits -> softmax -> argmax; also emit bf16 x ----------------
__global__ __launch_bounds__(256) void gating_kernel(
    const float* __restrict__ x, const float* __restrict__ wg,
    int* __restrict__ idx, float* __restrict__ gate,
    float* __restrict__ mepart, short* __restrict__ xb) {
  __shared__ float me_s[NEXP];
  int tid = threadIdx.x, wid = tid >> 6, lane = tid & 63;
  if (tid < NEXP) me_s[tid] = 0.f;
  __syncthreads();
  int t = blockIdx.x * 4 + wid;
  float acc[NEXP];
#pragma unroll
  for (int e = 0; e < NEXP; e++) acc[e] = 0.f;
  const float4* xr = (const float4*)(x + (size_t)t * MDIM);
  short* xbr = xb + (size_t)t * MDIM + lane * 16;
#pragma unroll
  for (int j = 0; j < 4; j++) {
    float4 xv = xr[lane * 4 + j];
    short4 bv; bv.x = f2bf(xv.x); bv.y = f2bf(xv.y); bv.z = f2bf(xv.z); bv.w = f2bf(xv.w);
    ((short4*)(xbr))[j] = bv;
    int base = lane * 16 + j * 4;
    const float* xp = &xv.x;
#pragma unroll
    for (int i = 0; i < 4; i++) {
      float xi = xp[i];
      const float4* wr = (const float4*)(wg + (size_t)(base + i) * NEXP);
      float4 w0 = wr[0], w1 = wr[1];
      acc[0] += xi * w0.x; acc[1] += xi * w0.y; acc[2] += xi * w0.z; acc[3] += xi * w0.w;
      acc[4] += xi * w1.x; acc[5] += xi * w1.y; acc[6] += xi * w1.z; acc[7] += xi * w1.w;
    }
  }
#pragma unroll
  for (int off = 32; off > 0; off >>= 1)
#pragma unroll
    for (int e = 0; e < NEXP; e++) acc[e] += __shfl_xor(acc[e], off, 64);
  if (lane == 0) {
    float mx = acc[0]; int ai = 0;
#pragma unroll
    for (int e = 1; e < NEXP; e++) if (acc[e] > mx) { mx = acc[e]; ai = e; }
    float ex[NEXP]; float se = 0.f;
#pragma unroll
    for (int e = 0; e < NEXP; e++) { ex[e] = __expf(acc[e] - mx); se += ex[e]; }
    float inv = 1.f / se;
#pragma unroll
    for (int e = 0; e < NEXP; e++) atomicAdd(&me_s[e], ex[e] * inv);
    idx[t] = ai;
    gate[t] = inv;
  }
  __syncthreads();
  if (tid < NEXP) mepart[blockIdx.x * NEXP + tid] = me_s[tid];
}

// ---------------- ordered scan: queue positions (2 barriers total) ----------------
__global__ __launch_bounds__(1024) void scan_kernel(
    const int* __restrict__ idx, float* __restrict__ gate,
    int* __restrict__ s2t, int* __restrict__ counts) {
  __shared__ int wcnt[16][NEXP];
  __shared__ int wbase[16][NEXP];
  int tid = threadIdx.x, wid = tid >> 6, lane = tid & 63;
  unsigned long long ltmask = (1ull << lane) - 1ull;
  int myexp[16], myloc[16];
  int cnt[NEXP];
#pragma unroll
  for (int e = 0; e < NEXP; e++) cnt[e] = 0;
  int base_tok = wid * 1024;
#pragma unroll
  for (int p = 0; p < 16; p++) {
    int e = idx[base_tok + p * 64 + lane];
    myexp[p] = e;
    int pos = 0;
#pragma unroll
    for (int e2 = 0; e2 < NEXP; e2++) {
      unsigned long long b = __ballot(e == e2);
      if (e == e2) pos = cnt[e2] + __popcll(b & ltmask);
      cnt[e2] += __popcll(b);            // wave-uniform
    }
    myloc[p] = pos;
  }
  if (lane < NEXP) wcnt[wid][lane] = cnt[lane];
  __syncthreads();
  if (tid < 128) {
    int w = tid >> 3, e = tid & 7;
    int s = 0;
    for (int w2 = 0; w2 < w; w2++) s += wcnt[w2][e];
    wbase[w][e] = s;
  }
  __syncthreads();
#pragma unroll
  for (int p = 0; p < 16; p++) {
    int i = base_tok + p * 64 + lane;
    int e = myexp[p];
    int loc = wbase[wid][e] + myloc[p];
    if (loc < CAP) s2t[e * CAP + loc] = i;
    else           gate[i] = 0.f;
  }
  if (tid < NEXP) {
    int tot = 0;
#pragma unroll
    for (int w = 0; w < 16; w++) tot += wcnt[w][tid];
    counts[tid] = tot;
  }
}

// ---------------- l_aux + exp_counts tail ----------------
__global__ __launch_bounds__(256) void finalize_kernel(
    const float* __restrict__ mepart, const int* __restrict__ counts,
    float* __restrict__ out_tail, int nblocks) {
  __shared__ float red[256];
  __shared__ float me[NEXP];
  int tid = threadIdx.x;
  float s = 0.f;
  int e = tid & 7;
  for (int r = tid >> 3; r < nblocks; r += 32) s += mepart[r * NEXP + e];
  red[tid] = s;
  __syncthreads();
  if (tid < NEXP) {
    float tsum = 0.f;
    for (int i = tid; i < 256; i += 8) tsum += red[i];
    me[tid] = tsum;
  }
  __syncthreads();
  if (tid == 0) {
    float la = 0.f;
    for (int k = 0; k < NEXP; k++)
      la += (me[k] / (float)TOKENS) * ((float)counts[k] / (float)TOKENS);
    out_tail[0] = la * (float)NEXP;
  }
  if (tid < NEXP) out_tail[1 + tid] = (float)counts[tid];
}

// ---------------- fp32 [E][R][C] -> bf16 [E][C][R], 64x64 LDS tiles ----------------
__global__ __launch_bounds__(256) void transpose_cvt_kernel(
    const float* __restrict__ in, short* __restrict__ out, int R, int Cc) {
  __shared__ short tile[64][72];   // pad 72: 8B-aligned b64 reads, <=2-way banks
  int e = blockIdx.z;
  const float* in_e = in + (size_t)e * R * Cc;
  short* out_e = out + (size_t)e * R * Cc;
  int r0 = blockIdx.y * 64, c0 = blockIdx.x * 64;
  int tid = threadIdx.x;
#pragma unroll
  for (int i = 0; i < 4; i++) {
    int linear = tid + 256 * i;          // 0..1023
    int r = linear >> 4;                 // 0..63
    int f4 = linear & 15;                // 0..15
    float4 v = *(const float4*)(in_e + (size_t)(r0 + r) * Cc + c0 + f4 * 4);
    int c = f4 * 4;
    tile[c + 0][r] = f2bf(v.x);
    tile[c + 1][r] = f2bf(v.y);
    tile[c + 2][r] = f2bf(v.z);
    tile[c + 3][r] = f2bf(v.w);
  }
  __syncthreads();
#pragma unroll
  for (int i = 0; i < 4; i++) {
    int linear = tid + 256 * i;
    int c = linear >> 4;
    int s4 = linear & 15;
    short4 s;
    s.x = tile[c][s4 * 4 + 0]; s.y = tile[c][s4 * 4 + 1];
    s.z = tile[c][s4 * 4 + 2]; s.w = tile[c][s4 * 4 + 3];
    *(short4*)(out_e + (size_t)(c0 + c) * R + r0 + s4 * 4) = s;
  }
}

// ---------------- pipeline phase boundaries (counted vmcnt + raw barrier) ----------------
// asm "memory" clobbers on both sides of the barrier pin plain LDS loads/stores
// and global_load_lds to their phase; vmcnt is counted (never 0 in steady state).
__device__ __forceinline__ void pe_vm8() {
  asm volatile("s_waitcnt vmcnt(8)" ::: "memory");
  __builtin_amdgcn_s_barrier();
  asm volatile("" ::: "memory");
}
__device__ __forceinline__ void pe_vm6() {
  asm volatile("s_waitcnt vmcnt(6)" ::: "memory");
  __builtin_amdgcn_s_barrier();
  asm volatile("" ::: "memory");
}
__device__ __forceinline__ void pe_vm0() {
  asm volatile("s_waitcnt vmcnt(0)" ::: "memory");
  __builtin_amdgcn_s_barrier();
  asm volatile("" ::: "memory");
}

#define GLL(gp, lp) __builtin_amdgcn_global_load_lds(                                   \
    (const __attribute__((address_space(1))) void*)(gp),                                \
    (__attribute__((address_space(3))) void*)(lp), 16, 0, 0)

// ---------------- GEMM1: 256x256xBK64, 8 waves, 4-phase pipelined K-loop ----------------
// A = gathered xb rows (cap dim), B = W1t [H][M]. MFMA operands swapped:
// D[col=lane&15 -> cap row][row=(lane>>4)*4+j -> H col].
// LDS swizzle: LDS(r, s) = G(r, s ^ (r&7)) at 8-short granularity (2-way-free banks).
// Stage units per K-tile: A0={rounds 0,2}=rows{0-63,128-191}, A1={1,3}, B0={(h0,j0),(h0,j1)}, B1={h1,*}.
// Phase reads: P1: af0(8)+bf0(4); P2: bf1(4); P3: af1(8); P4: none.
// Phase stages (tile t+2, into buf[t&1] after region consumed): P2: A0+B0(4); P3: B1(2); P4: A1(2).
// Ledger: 8 loads/tile in flight -> uniform vmcnt(8) per phase end is a no-op in
// steady state with >=4-phase prefetch lead; tail (t >= NKT1-2) drains with vmcnt(0).
__global__ __launch_bounds__(512, 2) void gemm1_kernel(
    const short* __restrict__ xb, const int* __restrict__ s2t,
    const short* __restrict__ W1t, const float* __restrict__ b1,
    short* __restrict__ Hh, const short* __restrict__ zrow, int eg) {
  __shared__ __align__(16) short ldsA[2][256 * 64];
  __shared__ __align__(16) short ldsB[2][256 * 64];
  int bz = blockIdx.z, bm = blockIdx.y, bn = blockIdx.x;
  int e_abs = eg + bz;
  int tid = threadIdx.x, lane = tid & 63, w = tid >> 6;
  int v = tid >> 3;                  // 0..63: row-within-round selector
  int sl = tid & 7;                  // source 16B slot selector

  // A staging pointers (token gather), rounds q=0..3: row = q*64 + v
  const short* aptr[4];
#pragma unroll
  for (int q = 0; q < 4; q++) {
    int r = q * 64 + v;
    int tok = s2t[e_abs * CAP + bm * 256 + r];
    const short* basep = (tok >= 0) ? (xb + (size_t)tok * MDIM) : zrow;
    aptr[q] = basep + ((sl ^ (r & 7)) * 8);
  }
  // B staging pointers, rounds (h,j): row = j*128 + (v>>5)*64 + (v&31) + h*32
  // (32-row interleave so each round lies entirely in one consumption half)
  const short* Be = W1t + ((size_t)e_abs * HDIM + (size_t)bn * 256) * MDIM;
  const short* bptr[2][2];
#pragma unroll
  for (int h = 0; h < 2; h++)
#pragma unroll
    for (int j = 0; j < 2; j++) {
      int r = j * 128 + (v >> 5) * 64 + (v & 31) + h * 32;
      bptr[h][j] = Be + (size_t)r * MDIM + ((sl ^ (r & 7)) * 8);
    }
  asm volatile("" ::: "memory");   // pin gather loads before first stage

  // wave-uniform LDS destination bases (shorts)
  int ldsa_base[4], ldsb_base[2][2];
#pragma unroll
  for (int q = 0; q < 4; q++) ldsa_base[q] = (q * 64 + w * 8) * 64;
#pragma unroll
  for (int h = 0; h < 2; h++)
#pragma unroll
    for (int j = 0; j < 2; j++)
      ldsb_base[h][j] = (j * 128 + h * 32 + (w >> 2) * 64 + (w & 3) * 8) * 64;

  // prologue: tiles 0 and 1 fully staged (order A0,B0,B1,A1 per tile)
  GLL(aptr[0] + 0,        &ldsA[0][ldsa_base[0]]);
  GLL(aptr[2] + 0,        &ldsA[0][ldsa_base[2]]);
  GLL(bptr[0][0] + 0,     &ldsB[0][ldsb_base[0][0]]);
  GLL(bptr[0][1] + 0,     &ldsB[0][ldsb_base[0][1]]);
  GLL(bptr[1][0] + 0,     &ldsB[0][ldsb_base[1][0]]);
  GLL(bptr[1][1] + 0,     &ldsB[0][ldsb_base[1][1]]);
  GLL(aptr[1] + 0,        &ldsA[0][ldsa_base[1]]);
  GLL(aptr[3] + 0,        &ldsA[0][ldsa_base[3]]);
  GLL(aptr[0] + 64,       &ldsA[1][ldsa_base[0]]);
  GLL(aptr[2] + 64,       &ldsA[1][ldsa_base[2]]);
  GLL(bptr[0][0] + 64,    &ldsB[1][ldsb_base[0][0]]);
  GLL(bptr[0][1] + 64,    &ldsB[1][ldsb_base[0][1]]);
  GLL(bptr[1][0] + 64,    &ldsB[1][ldsb_base[1][0]]);
  GLL(bptr[1][1] + 64,    &ldsB[1][ldsb_base[1][1]]);
  GLL(aptr[1] + 64,       &ldsA[1][ldsa_base[1]]);
  GLL(aptr[3] + 64,       &ldsA[1][ldsa_base[3]]);
  pe_vm8();                          // tile 0 landed; tile 1 (8 loads) in flight

  int wm = w >> 2, wn = w & 3;       // 2 x 4 wave grid; per-wave out = 128(cap) x 64(H)
  int ln = lane & 15, q4 = lane >> 4;
  int offk0 = ((q4 ^ (lane & 7)) * 8);
  int offk1 = (((4 + q4) ^ (lane & 7)) * 8);
  int arowbase = wm * 128 + ln;
  int browbase = wn * 64 + ln;

  f32x4 acc[8][4];
  f32x4 zero = {0.f, 0.f, 0.f, 0.f};
#pragma unroll
  for (int a = 0; a < 8; a++)
#pragma unroll
    for (int b = 0; b < 4; b++) acc[a][b] = zero;

  for (int t = 0; t < NKT1; ++t) {
    int cur = t & 1;
    const short* La = ldsA[cur];
    const short* Lb = ldsB[cur];
    int kts = (t + 2) * 64;
    bool st = (t + 2) < NKT1;
    bool steady = t < (NKT1 - 2);
    bf16x8 af[4][2], bf0[2][2], bf1[2][2];
    // ---- P1: read af-half0 + bf0; MFMA rt0-3 x ct0-1 ----
#pragma unroll
    for (int rt = 0; rt < 4; rt++) {
      int ro = (arowbase + rt * 16) * 64;
      af[rt][0] = *(const bf16x8*)(La + ro + offk0);
      af[rt][1] = *(const bf16x8*)(La + ro + offk1);
    }
#pragma unroll
    for (int c = 0; c < 2; c++) {
      int ro = (browbase + c * 16) * 64;
      bf0[c][0] = *(const bf16x8*)(Lb + ro + offk0);
      bf0[c][1] = *(const bf16x8*)(Lb + ro + offk1);
    }
    __builtin_amdgcn_s_setprio(1);
#pragma unroll
    for (int rt = 0; rt < 4; rt++)
#pragma unroll
      for (int c = 0; c < 2; c++) {
        acc[rt][c] = __builtin_amdgcn_mfma_f32_16x16x32_bf16(bf0[c][0], af[rt][0], acc[rt][c], 0, 0, 0);
        acc[rt][c] = __builtin_amdgcn_mfma_f32_16x16x32_bf16(bf0[c][1], af[rt][1], acc[rt][c], 0, 0, 0);
      }
    __builtin_amdgcn_s_setprio(0);
    if (steady) pe_vm8(); else pe_vm0();
    // ---- P2: read bf1; stage A0+B0(t+2); MFMA rt0-3 x ct2-3 ----
#pragma unroll
    for (int c = 0; c < 2; c++) {
      int ro = (browbase + (c + 2) * 16) * 64;
      bf1[c][0] = *(const bf16x8*)(Lb + ro + offk0);
      bf1[c][1] = *(const bf16x8*)(Lb + ro + offk1);
    }
    if (st) {
      GLL(aptr[0] + kts,    &ldsA[cur][ldsa_base[0]]);
      GLL(aptr[2] + kts,    &ldsA[cur][ldsa_base[2]]);
      GLL(bptr[0][0] + kts, &ldsB[cur][ldsb_base[0][0]]);
      GLL(bptr[0][1] + kts, &ldsB[cur][ldsb_base[0][1]]);
    }
    __builtin_amdgcn_s_setprio(1);
#pragma unroll
    for (int rt = 0; rt < 4; rt++)
#pragma unroll
      for (int c = 0; c < 2; c++) {
        acc[rt][c + 2] = __builtin_amdgcn_mfma_f32_16x16x32_bf16(bf1[c][0], af[rt][0], acc[rt][c + 2], 0, 0, 0);
        acc[rt][c + 2] = __builtin_amdgcn_mfma_f32_16x16x32_bf16(bf1[c][1], af[rt][1], acc[rt][c + 2], 0, 0, 0);
      }
    __builtin_amdgcn_s_setprio(0);
    if (steady) pe_vm8(); else pe_vm0();
    // ---- P3: read af-half1; stage B1(t+2); MFMA rt4-7 x ct0-1 ----
#pragma unroll
    for (int rt = 0; rt < 4; rt++) {
      int ro = (arowbase + 64 + rt * 16) * 64;
      af[rt][0] = *(const bf16x8*)(La + ro + offk0);
      af[rt][1] = *(const bf16x8*)(La + ro + offk1);
    }
    if (st) {
      GLL(bptr[1][0] + kts, &ldsB[cur][ldsb_base[1][0]]);
      GLL(bptr[1][1] + kts, &ldsB[cur][ldsb_base[1][1]]);
    }
    __builtin_amdgcn_s_setprio(1);
#pragma unroll
    for (int rt = 0; rt < 4; rt++)
#pragma unroll
      for (int c = 0; c < 2; c++) {
        acc[4 + rt][c] = __builtin_amdgcn_mfma_f32_16x16x32_bf16(bf0[c][0], af[rt][0], acc[4 + rt][c], 0, 0, 0);
        acc[4 + rt][c] = __builtin_amdgcn_mfma_f32_16x16x32_bf16(bf0[c][1], af[rt][1], acc[4 + rt][c], 0, 0, 0);
      }
    __builtin_amdgcn_s_setprio(0);
    if (steady) pe_vm8(); else pe_vm0();
    // ---- P4: stage A1(t+2); MFMA rt4-7 x ct2-3 ----
    if (st) {
      GLL(aptr[1] + kts,    &ldsA[cur][ldsa_base[1]]);
      GLL(aptr[3] + kts,    &ldsA[cur][ldsa_base[3]]);
    }
    __builtin_amdgcn_s_setprio(1);
#pragma unroll
    for (int rt = 0; rt < 4; rt++)
#pragma unroll
      for (int c = 0; c < 2; c++) {
        acc[4 + rt][c + 2] = __builtin_amdgcn_mfma_f32_16x16x32_bf16(bf1[c][0], af[rt][0], acc[4 + rt][c + 2], 0, 0, 0);
        acc[4 + rt][c + 2] = __builtin_amdgcn_mfma_f32_16x16x32_bf16(bf1[c][1], af[rt][1], acc[4 + rt][c + 2], 0, 0, 0);
      }
    __builtin_amdgcn_s_setprio(0);
    if (steady) pe_vm8(); else pe_vm0();
  }

  // epilogue: gelu + bias -> bf16 pack -> 8B stores
#pragma unroll
  for (int rt = 0; rt < 8; rt++) {
    int caprow = bm * 256 + wm * 128 + rt * 16 + ln;
    size_t rowoff = ((size_t)bz * CAP + caprow) * HDIM;
#pragma unroll
    for (int c = 0; c < 4; c++) {
      int colb = bn * 256 + wn * 64 + c * 16 + q4 * 4;
      float4 bias = *(const float4*)(b1 + (size_t)e_abs * HDIM + colb);
      unsigned u0 = bfbits(gelu_f(acc[rt][c][0] + bias.x));
      unsigned u1 = bfbits(gelu_f(acc[rt][c][1] + bias.y));
      unsigned u2 = bfbits(gelu_f(acc[rt][c][2] + bias.z));
      unsigned u3 = bfbits(gelu_f(acc[rt][c][3] + bias.w));
      uint2 pk;
      pk.x = __builtin_amdgcn_perm(u1, u0, 0x07060302u);
      pk.y = __builtin_amdgcn_perm(u3, u2, 0x07060302u);
      *(uint2*)(Hh + rowoff + colb) = pk;
    }
  }
}

// ---------------- GEMM2: 128x256xBK64, 8 waves, 2-phase pipelined; fused combine ----------------
// A = Hh [cap][H] (dense), B = W2t [M][H]. Per-wave out = 64(cap) x 64(M).
// Stage units/K-tile: A0 (rows {0-31,64-95}, 1 load), A1 (+32, 1 load), B (4 loads).
// Reads: P1: af0(4)+bf(8); P2: af1(4).  Stages: P1: A1(t+1)->buf[cur^1]; P2: A0,B(t+2)->buf[cur].
// Ledger (FIFO): end-P1 needs oldest 1 -> vmcnt(6); end-P2 needs oldest 5 -> vmcnt(6). Tail: vmcnt(0).
__global__ __launch_bounds__(512, 2) void gemm2_kernel(
    const short* __restrict__ Hh, const short* __restrict__ W2t,
    const float* __restrict__ b2, const int* __restrict__ s2t,
    const float* __restrict__ gate, float* __restrict__ out, int eg) {
  __shared__ __align__(16) short ldsA[2][128 * 64];
  __shared__ __align__(16) short ldsB[2][256 * 64];
  int bz = blockIdx.z, bm = blockIdx.y, bn = blockIdx.x;
  int e_abs = eg + bz;
  int tid = threadIdx.x, lane = tid & 63, w = tid >> 6;
  int v = tid >> 3, sl = tid & 7;
  const short* Ae = Hh + ((size_t)bz * CAP + (size_t)bm * 128) * HDIM;
  const short* Be = W2t + ((size_t)e_abs * MDIM + (size_t)bn * 256) * HDIM;
  const short* aptr[2];
#pragma unroll
  for (int h = 0; h < 2; h++) {
    int r = (v >> 5) * 64 + (v & 31) + h * 32;   // 32-row interleave: half h = P(h+1)'s rows
    aptr[h] = Ae + (size_t)r * HDIM + ((sl ^ (r & 7)) * 8);
  }
  const short* bptr[4];
#pragma unroll
  for (int q = 0; q < 4; q++) {
    int r = q * 64 + v;
    bptr[q] = Be + (size_t)r * HDIM + ((sl ^ (r & 7)) * 8);
  }
  int ldsa_base[2], ldsb_base[4];
#pragma unroll
  for (int h = 0; h < 2; h++) ldsa_base[h] = (h * 32 + (w >> 2) * 64 + (w & 3) * 8) * 64;
#pragma unroll
  for (int q = 0; q < 4; q++) ldsb_base[q] = (q * 64 + w * 8) * 64;

  // prologue: A0(0), B(0), A1(0), A0(1), B(1)  -> wait oldest 6 (tile 0)
  GLL(aptr[0] + 0,  &ldsA[0][ldsa_base[0]]);
  GLL(bptr[0] + 0,  &ldsB[0][ldsb_base[0]]);
  GLL(bptr[1] + 0,  &ldsB[0][ldsb_base[1]]);
  GLL(bptr[2] + 0,  &ldsB[0][ldsb_base[2]]);
  GLL(bptr[3] + 0,  &ldsB[0][ldsb_base[3]]);
  GLL(aptr[1] + 0,  &ldsA[0][ldsa_base[1]]);
  GLL(aptr[0] + 64, &ldsA[1][ldsa_base[0]]);
  GLL(bptr[0] + 64, &ldsB[1][ldsb_base[0]]);
  GLL(bptr[1] + 64, &ldsB[1][ldsb_base[1]]);
  GLL(bptr[2] + 64, &ldsB[1][ldsb_base[2]]);
  GLL(bptr[3] + 64, &ldsB[1][ldsb_base[3]]);
  asm volatile("s_waitcnt vmcnt(5)" ::: "memory");
  __builtin_amdgcn_s_barrier();
  asm volatile("" ::: "memory");

  int wm = w >> 2, wn = w & 3;
  int ln = lane & 15, q4 = lane >> 4;
  int offk0 = ((q4 ^ (lane & 7)) * 8);
  int offk1 = (((4 + q4) ^ (lane & 7)) * 8);
  int arowbase = wm * 64 + ln;
  int browbase = wn * 64 + ln;

  f32x4 acc[4][4];
  f32x4 zero = {0.f, 0.f, 0.f, 0.f};
#pragma unroll
  for (int a = 0; a < 4; a++)
#pragma unroll
    for (int b = 0; b < 4; b++) acc[a][b] = zero;

  for (int t = 0; t < NKT2; ++t) {
    int cur = t & 1;
    const short* La = ldsA[cur];
    const short* Lb = ldsB[cur];
    bool steady = t < (NKT2 - 2);
    bf16x8 af[2][2], bf[4][2];
    // ---- P1: read af-half0 + bf(all); stage A1(t+1); MFMA rt0-1 x ct0-3 ----
#pragma unroll
    for (int rt = 0; rt < 2; rt++) {
      int ro = (arowbase + rt * 16) * 64;
      af[rt][0] = *(const bf16x8*)(La + ro + offk0);
      af[rt][1] = *(const bf16x8*)(La + ro + offk1);
    }
#pragma unroll
    for (int c = 0; c < 4; c++) {
      int ro = (browbase + c * 16) * 64;
      bf[c][0] = *(const bf16x8*)(Lb + ro + offk0);
      bf[c][1] = *(const bf16x8*)(Lb + ro + offk1);
    }
    if (t + 1 < NKT2) { GLL(aptr[1] + (t + 1) * 64, &ldsA[cur ^ 1][ldsa_base[1]]); }
    __builtin_amdgcn_s_setprio(1);
#pragma unroll
    for (int rt = 0; rt < 2; rt++)
#pragma unroll
      for (int c = 0; c < 4; c++) {
        acc[rt][c] = __builtin_amdgcn_mfma_f32_16x16x32_bf16(bf[c][0], af[rt][0], acc[rt][c], 0, 0, 0);
        acc[rt][c] = __builtin_amdgcn_mfma_f32_16x16x32_bf16(bf[c][1], af[rt][1], acc[rt][c], 0, 0, 0);
      }
    __builtin_amdgcn_s_setprio(0);
    if (steady) pe_vm6(); else pe_vm0();
    // ---- P2: read af-half1; stage A0+B(t+2); MFMA rt2-3 x ct0-3 ----
#pragma unroll
    for (int rt = 0; rt < 2; rt++) {
      int ro = (arowbase + 32 + rt * 16) * 64;
      af[rt][0] = *(const bf16x8*)(La + ro + offk0);
      af[rt][1] = *(const bf16x8*)(La + ro + offk1);
    }
    if (t + 2 < NKT2) {
      int kts = (t + 2) * 64;
      GLL(aptr[0] + kts, &ldsA[cur][ldsa_base[0]]);
      GLL(bptr[0] + kts, &ldsB[cur][ldsb_base[0]]);
      GLL(bptr[1] + kts, &ldsB[cur][ldsb_base[1]]);
      GLL(bptr[2] + kts, &ldsB[cur][ldsb_base[2]]);
      GLL(bptr[3] + kts, &ldsB[cur][ldsb_base[3]]);
    }
    __builtin_amdgcn_s_setprio(1);
#pragma unroll
    for (int rt = 0; rt < 2; rt++)
#pragma unroll
      for (int c = 0; c < 4; c++) {
        acc[2 + rt][c] = __builtin_amdgcn_mfma_f32_16x16x32_bf16(bf[c][0], af[rt][0], acc[2 + rt][c], 0, 0, 0);
        acc[2 + rt][c] = __builtin_amdgcn_mfma_f32_16x16x32_bf16(bf[c][1], af[rt][1], acc[2 + rt][c], 0, 0, 0);
      }
    __builtin_amdgcn_s_setprio(0);
    if (steady) pe_vm6(); else pe_vm0();
  }

  // epilogue: bias + gate scale, scatter to token rows
#pragma unroll
  for (int rt = 0; rt < 4; rt++) {
    int caprow = bm * 128 + wm * 64 + rt * 16 + ln;
    int token = s2t[e_abs * CAP + caprow];
    if (token < 0) continue;
    float g = gate[token];
    float* orow = out + (size_t)token * MDIM;
#pragma unroll
    for (int c = 0; c < 4; c++) {
      int colb = bn * 256 + wn * 64 + c * 16 + q4 * 4;
      float4 bias = *(const float4*)(b2 + (size_t)e_abs * MDIM + colb);
      float4 vv;
      vv.x = (acc[rt][c][0] + bias.x) * g;
      vv.y = (acc[rt][c][1] + bias.y) * g;
      vv.z = (acc[rt][c][2] + bias.z) * g;
      vv.w = (acc[rt][c][3] + bias.w) * g;
      *(float4*)(orow + colb) = vv;
    }
  }
}

// ---------------- zero rows of dropped tokens ----------------
__global__ __launch_bounds__(256) void zerodrop_kernel(
    const float* __restrict__ gate, float* __restrict__ out) {
  int t = blockIdx.x;
  if (gate[t] != 0.f) return;
  float4 z = {0.f, 0.f, 0.f, 0.f};
  ((float4*)(out + (size_t)t * MDIM))[threadIdx.x] = z;
}

extern "C" void kernel_launch(void* const* d_in, const int* in_sizes, int n_in,
                              void* d_out, int out_size, void* d_ws, size_t ws_size,
                              hipStream_t stream) {
  const float* x  = (const float*)d_in[0];
  const float* wg = (const float*)d_in[1];
  const float* w1 = (const float*)d_in[2];
  const float* b1 = (const float*)d_in[3];
  const float* w2 = (const float*)d_in[4];
  const float* b2 = (const float*)d_in[5];
  float* out = (float*)d_out;

  char* ws = (char*)d_ws;
  size_t off = 0;
  auto alloc = [&](size_t n) { char* ptr = ws + off; off += (n + 255) & ~(size_t)255; return ptr; };
  short* W1t  = (short*)alloc((size_t)NEXP * MDIM * HDIM * 2);   // 67 MB [E][H][M]
  short* W2t  = (short*)alloc((size_t)NEXP * MDIM * HDIM * 2);   // 67 MB [E][M][H]
  short* Hh   = (short*)alloc((size_t)EGRP * CAP * HDIM * 2);    // 67 MB (4 experts, full H)
  short* xb   = (short*)alloc((size_t)TOKENS * MDIM * 2);        // 33.5 MB bf16 x
  short* zrow = (short*)alloc((size_t)MDIM * 2);
  int*   idx  = (int*)  alloc(TOKENS * 4);
  float* gate = (float*)alloc(TOKENS * 4);
  int*   s2t  = (int*)  alloc(NEXP * CAP * 4);
  float* mep  = (float*)alloc((TOKENS / 4) * NEXP * 4);
  int*   cnts = (int*)  alloc(NEXP * 4);
  if (ws_size < off) return;

  hipMemsetAsync(s2t, 0xFF, NEXP * CAP * 4, stream);  // -1 sentinels
  hipMemsetAsync(zrow, 0, MDIM * 2, stream);

  gating_kernel<<<TOKENS / 4, 256, 0, stream>>>(x, wg, idx, gate, mep, xb);
  scan_kernel<<<1, 1024, 0, stream>>>(idx, gate, s2t, cnts);
  finalize_kernel<<<1, 256, 0, stream>>>(mep, cnts, out + (size_t)TOKENS * MDIM, TOKENS / 4);
  transpose_cvt_kernel<<<dim3(HDIM / 64, MDIM / 64, NEXP), 256, 0, stream>>>(w1, W1t, MDIM, HDIM);
  transpose_cvt_kernel<<<dim3(MDIM / 64, HDIM / 64, NEXP), 256, 0, stream>>>(w2, W2t, HDIM, MDIM);
  for (int g = 0; g < 2; g++) {
    gemm1_kernel<<<dim3(HDIM / 256, CAP / 256, EGRP), 512, 0, stream>>>(xb, s2t, W1t, b1, Hh, zrow, g * EGRP);
    gemm2_kernel<<<dim3(MDIM / 256, CAP / 128, EGRP), 512, 0, stream>>>(Hh, W2t, b2, s2t, gate, out, g * EGRP);
  }
  zerodrop_kernel<<<TOKENS, 256, 0, stream>>>(gate, out);
}